// Round 2
// baseline (452.999 us; speedup 1.0000x reference)
//
#include <hip/hip_runtime.h>
#include <math.h>

#define B 4096
#define D 512
#define MARGIN 0.3f
#define EPSD 1e-12f

#define NSEG 32            // one 128-col tile per block now
#define ROWTILE 128
#define CTILE 128
#define BK 32

// ---------------------------------------------------------------------------
// Kernel 1: squared norms, one wave per row.
// ---------------------------------------------------------------------------
__global__ __launch_bounds__(256) void sqnorm_kernel(const float* __restrict__ E,
                                                     float* __restrict__ sq) {
    int w    = (blockIdx.x * 256 + threadIdx.x) >> 6;
    int lane = threadIdx.x & 63;
    const float4* row = (const float4*)(E + (size_t)w * D);
    float4 a = row[lane];
    float4 b = row[lane + 64];
    float s = a.x * a.x + a.y * a.y + a.z * a.z + a.w * a.w
            + b.x * b.x + b.y * b.y + b.z * b.z + b.w * b.w;
#pragma unroll
    for (int o = 32; o; o >>= 1) s += __shfl_down(s, o);
    if (lane == 0) sq[w] = s;
}

// ---------------------------------------------------------------------------
// Kernel 2: fused distance + batch-hard mining. One 128x128 tile per block.
// Grid: 32 row-tiles x 32 col-tiles = 1024 blocks = 4 blocks/CU.
// LDS staged [k][row] with XOR swizzle: physical col = row ^ ((k>>2)<<2).
//   Writes: bank = (16*k4 + 4c + row^(k4<<2)) mod 32 -> exactly 2 lanes/bank (free).
//   B-reads (b128, addr varies with tx): 16 unique 16B slots -> 2-way (free).
//   A-reads: broadcast across tx (free).
// ---------------------------------------------------------------------------
__global__ __launch_bounds__(256, 4) void mine_kernel(const float* __restrict__ E,
                                                      const int* __restrict__ labels,
                                                      const float* __restrict__ sq,
                                                      float* __restrict__ hp_part,
                                                      float* __restrict__ hn_part) {
    __shared__ float a_t[BK][ROWTILE + 4];
    __shared__ float b_t[BK][CTILE + 4];
    __shared__ float sqc_s[CTILE];
    __shared__ int   lab_s[CTILE];

    const int tid = threadIdx.x;
    const int tx  = tid & 15;
    const int ty  = tid >> 4;
    const int r0  = (blockIdx.x & 31) * ROWTILE;
    const int seg = blockIdx.x >> 5;
    const int c0  = seg * CTILE;

    float hp[8], hn[8];
    float sq_i[8];
    int   lab_i[8];
#pragma unroll
    for (int i = 0; i < 8; ++i) {
        int rl = ty * 4 + (i & 3) + (i >> 2) * 64;
        hp[i] = -INFINITY;
        hn[i] = INFINITY;
        sq_i[i]  = sq[r0 + rl];
        lab_i[i] = labels[r0 + rl];
    }
    if (tid < CTILE) {
        sqc_s[tid] = sq[c0 + tid];
        lab_s[tid] = labels[c0 + tid];
    }

    float acc[8][8];
#pragma unroll
    for (int i = 0; i < 8; ++i)
#pragma unroll
        for (int j = 0; j < 8; ++j) acc[i][j] = 0.f;

    const int k4 = tid & 7;              // constant per thread (256 % 8 == 0)
    const int rb = tid >> 3;             // base row (0..31), +32 per chunk

    for (int kk = 0; kk < D; kk += BK) {
        if (kk) __syncthreads();         // previous compute done reading LDS
#pragma unroll
        for (int i = 0; i < 4; ++i) {
            int row  = rb + i * 32;
            int rowS = row ^ (k4 << 2);  // swizzle
            float4 v = *(const float4*)(E + (size_t)(r0 + row) * D + kk + k4 * 4);
            a_t[k4 * 4 + 0][rowS] = v.x;
            a_t[k4 * 4 + 1][rowS] = v.y;
            a_t[k4 * 4 + 2][rowS] = v.z;
            a_t[k4 * 4 + 3][rowS] = v.w;
        }
#pragma unroll
        for (int i = 0; i < 4; ++i) {
            int row  = rb + i * 32;
            int rowS = row ^ (k4 << 2);
            float4 v = *(const float4*)(E + (size_t)(c0 + row) * D + kk + k4 * 4);
            b_t[k4 * 4 + 0][rowS] = v.x;
            b_t[k4 * 4 + 1][rowS] = v.y;
            b_t[k4 * 4 + 2][rowS] = v.z;
            b_t[k4 * 4 + 3][rowS] = v.w;
        }
        __syncthreads();

#pragma unroll
        for (int k = 0; k < BK; ++k) {
            const int xs = (k & 28);     // ((k>>2)<<2)
            float4 a0 = *(const float4*)&a_t[k][(ty * 4) ^ xs];
            float4 a1 = *(const float4*)&a_t[k][(64 + ty * 4) ^ xs];
            float4 b0 = *(const float4*)&b_t[k][(tx * 4) ^ xs];
            float4 b1 = *(const float4*)&b_t[k][(64 + tx * 4) ^ xs];
            float av[8] = {a0.x, a0.y, a0.z, a0.w, a1.x, a1.y, a1.z, a1.w};
            float bv[8] = {b0.x, b0.y, b0.z, b0.w, b1.x, b1.y, b1.z, b1.w};
#pragma unroll
            for (int i = 0; i < 8; ++i)
#pragma unroll
                for (int j = 0; j < 8; ++j) acc[i][j] += av[i] * bv[j];
        }
    }

    // epilogue: dot -> distance -> masked hardest pos/neg
#pragma unroll
    for (int i = 0; i < 8; ++i) {
        const int rl = ty * 4 + (i & 3) + (i >> 2) * 64;
        const int ri = r0 + rl;
        const float sqi = sq_i[i];
        const int   li  = lab_i[i];
#pragma unroll
        for (int j = 0; j < 8; ++j) {
            const int cl = tx * 4 + (j & 3) + (j >> 2) * 64;
            const int cj = c0 + cl;
            float d2   = sqi + sqc_s[cl] - 2.f * acc[i][j];
            float dist = sqrtf(fmaxf(d2, EPSD));
            bool same  = (li == lab_s[cl]);
            bool diag  = (ri == cj);
            if (same && !diag) hp[i] = fmaxf(hp[i], dist);
            if (!same)         hn[i] = fminf(hn[i], dist);
        }
    }

    // reduce across tx (lane bits 0..3)
#pragma unroll
    for (int i = 0; i < 8; ++i) {
#pragma unroll
        for (int m = 1; m < 16; m <<= 1) {
            hp[i] = fmaxf(hp[i], __shfl_xor(hp[i], m));
            hn[i] = fminf(hn[i], __shfl_xor(hn[i], m));
        }
    }
    if (tx == 0) {
#pragma unroll
        for (int i = 0; i < 8; ++i) {
            int rl = ty * 4 + (i & 3) + (i >> 2) * 64;
            hp_part[seg * B + r0 + rl] = hp[i];
            hn_part[seg * B + r0 + rl] = hn[i];
        }
    }
}

// ---------------------------------------------------------------------------
// Kernel 3: combine segments, masked mean of relu(hp-hn+margin).
// ---------------------------------------------------------------------------
__global__ __launch_bounds__(256) void finalize_kernel(const float* __restrict__ hp_part,
                                                       const float* __restrict__ hn_part,
                                                       float* __restrict__ out) {
    const int tid = threadIdx.x;
    float sum = 0.f, cnt = 0.f;
    for (int r = tid; r < B; r += 256) {
        float hp = -INFINITY, hn = INFINITY;
#pragma unroll
        for (int s = 0; s < NSEG; ++s) {
            hp = fmaxf(hp, hp_part[s * B + r]);
            hn = fminf(hn, hn_part[s * B + r]);
        }
        bool valid = (hp > -INFINITY) && (hn < INFINITY);
        if (valid) {
            sum += fmaxf(hp - hn + MARGIN, 0.f);
            cnt += 1.f;
        }
    }
#pragma unroll
    for (int o = 32; o; o >>= 1) {
        sum += __shfl_down(sum, o);
        cnt += __shfl_down(cnt, o);
    }
    __shared__ float ssum[4], scnt[4];
    int lane = tid & 63, wv = tid >> 6;
    if (lane == 0) { ssum[wv] = sum; scnt[wv] = cnt; }
    __syncthreads();
    if (tid == 0) {
        float S = 0.f, C = 0.f;
#pragma unroll
        for (int i = 0; i < 4; ++i) { S += ssum[i]; C += scnt[i]; }
        out[0] = (C > 0.f) ? S / fmaxf(C, 1.f) : 0.f;
    }
}

// ---------------------------------------------------------------------------
extern "C" void kernel_launch(void* const* d_in, const int* in_sizes, int n_in,
                              void* d_out, int out_size, void* d_ws, size_t ws_size,
                              hipStream_t stream) {
    const float* E      = (const float*)d_in[0];
    const int*   labels = (const int*)d_in[1];
    float* out = (float*)d_out;
    float* ws  = (float*)d_ws;

    float* sq      = ws;                 // B floats
    float* hp_part = ws + B;             // NSEG*B floats
    float* hn_part = ws + B + NSEG * B;  // NSEG*B floats

    sqnorm_kernel<<<B / 4, 256, 0, stream>>>(E, sq);
    mine_kernel<<<32 * 32, 256, 0, stream>>>(E, labels, sq, hp_part, hn_part);
    finalize_kernel<<<1, 256, 0, stream>>>(hp_part, hn_part, out);
}

// Round 4
// 144.912 us; speedup vs baseline: 3.1260x; 3.1260x over previous
//
#include <hip/hip_runtime.h>
#include <math.h>

typedef unsigned short ushort_t;
typedef unsigned int uint_t;
typedef __attribute__((ext_vector_type(8))) short short8;   // 8 bf16 (4 VGPRs)
typedef __attribute__((ext_vector_type(4))) float f32x4;    // MFMA acc

#define B 4096
#define D 512
#define MARGIN 0.3f
#define EPSD 1e-12f
#define NSEG 64            // 32 col-tiles x 2 col-half-waves

__device__ inline ushort_t f2bf_rn(float x) {
    uint_t u = __float_as_uint(x);
    uint_t r = (u + 0x7fffu + ((u >> 16) & 1u)) >> 16;
    return (ushort_t)r;
}
__device__ inline float bf2f(ushort_t h) {
    return __uint_as_float(((uint_t)h) << 16);
}
__device__ inline void gload_lds16(const void* g, void* l) {
    __builtin_amdgcn_global_load_lds(
        (const __attribute__((address_space(1))) void*)g,
        (__attribute__((address_space(3))) void*)l, 16, 0, 0);
}

// ---------------------------------------------------------------------------
// Kernel 1: per-row sqnorm + fp32 -> (bf16 hi, bf16 lo) split. One wave/row.
// Also zeroes the sum/count accumulators (gid 0).
// ---------------------------------------------------------------------------
__global__ __launch_bounds__(256) void prep_kernel(const float* __restrict__ E,
                                                   float* __restrict__ sq,
                                                   ushort_t* __restrict__ Ehi,
                                                   ushort_t* __restrict__ Elo,
                                                   float* __restrict__ sumcnt) {
    int gid  = blockIdx.x * 256 + threadIdx.x;
    int w    = gid >> 6;          // row
    int lane = gid & 63;
    const float4* row = (const float4*)(E + (size_t)w * D);
    float4 a = row[lane];
    float4 b = row[lane + 64];

    float s = a.x * a.x + a.y * a.y + a.z * a.z + a.w * a.w
            + b.x * b.x + b.y * b.y + b.z * b.z + b.w * b.w;
#pragma unroll
    for (int o = 32; o; o >>= 1) s += __shfl_down(s, o);
    if (lane == 0) sq[w] = s;

    float va[8] = {a.x, a.y, a.z, a.w, b.x, b.y, b.z, b.w};
    ushort_t hi[8], lo[8];
#pragma unroll
    for (int i = 0; i < 8; ++i) {
        hi[i] = f2bf_rn(va[i]);
        lo[i] = f2bf_rn(va[i] - bf2f(hi[i]));
    }
    ushort4* ph = (ushort4*)(Ehi + (size_t)w * D);
    ushort4* pl = (ushort4*)(Elo + (size_t)w * D);
    ph[lane]      = make_ushort4(hi[0], hi[1], hi[2], hi[3]);
    ph[lane + 64] = make_ushort4(hi[4], hi[5], hi[6], hi[7]);
    pl[lane]      = make_ushort4(lo[0], lo[1], lo[2], lo[3]);
    pl[lane + 64] = make_ushort4(lo[4], lo[5], lo[6], lo[7]);

    if (gid == 0) { sumcnt[0] = 0.f; sumcnt[1] = 0.f; }
}

// ---------------------------------------------------------------------------
// Kernel 2: MFMA distance + batch-hard mining. 128x128 tile/block, 4 waves 2x2.
// dot = hi.hi + hi.lo + lo.hi  (3 K-segments of 512 -> effective K=1536).
// LDS [128 rows][32 k] bf16, 64 B/row; phys 16B-slot = logical ^ ((row>>1)&3)
// (pre-swizzled global source, linear global_load_lds dest; reads 2-way = free).
// ---------------------------------------------------------------------------
__global__ __launch_bounds__(256) void mine_mfma(const ushort_t* __restrict__ Ehi,
                                                 const ushort_t* __restrict__ Elo,
                                                 const int* __restrict__ labels,
                                                 const float* __restrict__ sq,
                                                 float* __restrict__ hp_part,
                                                 float* __restrict__ hn_part) {
    __shared__ short8 a8[512];               // 8 KB: A tile
    __shared__ short8 b8[512];               // 8 KB: B tile
    __shared__ float  sqr_s[128], sqc_s[128];
    __shared__ int    labr_s[128], labc_s[128];
    char* aB = (char*)a8;
    char* bB = (char*)b8;

    const int tid = threadIdx.x;
    const int w   = tid >> 6;                // wave 0..3
    const int l   = tid & 63;
    const int rt  = blockIdx.x & 31;
    const int ct  = blockIdx.x >> 5;
    const int r0  = rt * 128;
    const int c0  = ct * 128;
    const int wm  = w >> 1;                  // 0..1 row-half
    const int wn  = w & 1;                   // 0..1 col-half

    if (tid < 128) {
        sqr_s[tid]  = sq[r0 + tid];
        labr_s[tid] = labels[r0 + tid];
    } else {
        int t = tid - 128;
        sqc_s[t]  = sq[c0 + t];
        labc_s[t] = labels[c0 + t];
    }

    f32x4 acc[4][4] = {};

    // staging geometry (per wave): rows [w*32, w*32+32), 2 gloads of 16 rows each
    const int srow  = (l >> 2);              // 0..15 within a 16-row group
    const int pslot = (l & 3);               // phys 16B slot

    for (int t = 0; t < 48; ++t) {
        const int seg = t >> 4;
        const int kk  = (t & 15) * 32;       // element offset in [0,512)
        const ushort_t* As = (seg == 2) ? Elo : Ehi;
        const ushort_t* Bs = (seg == 1) ? Elo : Ehi;

        if (t) __syncthreads();              // prev compute done reading LDS
#pragma unroll
        for (int i = 0; i < 2; ++i) {
            int rowL  = w * 32 + i * 16 + srow;
            int chunk = pslot ^ ((rowL >> 1) & 3);     // logical 16B chunk
            gload_lds16(As + (size_t)(r0 + rowL) * D + kk + chunk * 8,
                        aB + (w * 32 + i * 16) * 64);
            gload_lds16(Bs + (size_t)(c0 + rowL) * D + kk + chunk * 8,
                        bB + (w * 32 + i * 16) * 64);
        }
        __syncthreads();                      // compiler drains vmcnt before barrier

        short8 af[4], bf[4];
#pragma unroll
        for (int f = 0; f < 4; ++f) {
            int rrA = wm * 64 + f * 16 + (l & 15);
            int sA  = (l >> 4) ^ ((rrA >> 1) & 3);
            af[f] = *(const short8*)(aB + rrA * 64 + sA * 16);
            int rrB = wn * 64 + f * 16 + (l & 15);
            int sB  = (l >> 4) ^ ((rrB >> 1) & 3);
            bf[f] = *(const short8*)(bB + rrB * 64 + sB * 16);
        }
#pragma unroll
        for (int fm = 0; fm < 4; ++fm)
#pragma unroll
            for (int fn = 0; fn < 4; ++fn)
                acc[fm][fn] = __builtin_amdgcn_mfma_f32_16x16x32_bf16(
                    af[fm], bf[fn], acc[fm][fn], 0, 0, 0);
    }

    // epilogue: C/D layout col = lane&15, row = (lane>>4)*4 + reg  [m89]
#pragma unroll
    for (int fm = 0; fm < 4; ++fm) {
        const int rbase = wm * 64 + fm * 16 + ((l >> 4) << 2);
        float hp[4], hn[4], sqr[4];
        int   labr[4];
#pragma unroll
        for (int r = 0; r < 4; ++r) {
            sqr[r]  = sqr_s[rbase + r];
            labr[r] = labr_s[rbase + r];
            hp[r] = -INFINITY;
            hn[r] =  INFINITY;
        }
#pragma unroll
        for (int fn = 0; fn < 4; ++fn) {
            const int cl   = wn * 64 + fn * 16 + (l & 15);
            const float sqc = sqc_s[cl];
            const int  labc = labc_s[cl];
            const int  gcol = c0 + cl;
#pragma unroll
            for (int r = 0; r < 4; ++r) {
                float d2   = sqr[r] + sqc - 2.f * acc[fm][fn][r];
                float dist = sqrtf(fmaxf(d2, EPSD));
                bool same  = (labr[r] == labc);
                bool diag  = ((r0 + rbase + r) == gcol);
                if (same && !diag) hp[r] = fmaxf(hp[r], dist);
                if (!same)         hn[r] = fminf(hn[r], dist);
            }
        }
#pragma unroll
        for (int r = 0; r < 4; ++r) {
#pragma unroll
            for (int m = 1; m < 16; m <<= 1) {
                hp[r] = fmaxf(hp[r], __shfl_xor(hp[r], m));
                hn[r] = fminf(hn[r], __shfl_xor(hn[r], m));
            }
        }
        if ((l & 15) == 0) {
            const int p = ct * 2 + wn;
#pragma unroll
            for (int r = 0; r < 4; ++r) {
                hp_part[(size_t)p * B + r0 + rbase + r] = hp[r];
                hn_part[(size_t)p * B + r0 + rbase + r] = hn[r];
            }
        }
    }
}

// ---------------------------------------------------------------------------
// Kernel 3: per-row combine over 64 segments, block-reduce, atomic accumulate.
// ---------------------------------------------------------------------------
__global__ __launch_bounds__(256) void finalize1(const float* __restrict__ hp_part,
                                                 const float* __restrict__ hn_part,
                                                 float* __restrict__ sumcnt) {
    const int r = blockIdx.x * 256 + threadIdx.x;
    float hp = -INFINITY, hn = INFINITY;
#pragma unroll 8
    for (int s = 0; s < NSEG; ++s) {
        hp = fmaxf(hp, hp_part[(size_t)s * B + r]);
        hn = fminf(hn, hn_part[(size_t)s * B + r]);
    }
    bool valid = (hp > -INFINITY) && (hn < INFINITY);
    float loss = valid ? fmaxf(hp - hn + MARGIN, 0.f) : 0.f;
    float cnt  = valid ? 1.f : 0.f;
#pragma unroll
    for (int o = 32; o; o >>= 1) {
        loss += __shfl_down(loss, o);
        cnt  += __shfl_down(cnt, o);
    }
    __shared__ float ls[4], cs[4];
    int lane = threadIdx.x & 63, wv = threadIdx.x >> 6;
    if (lane == 0) { ls[wv] = loss; cs[wv] = cnt; }
    __syncthreads();
    if (threadIdx.x == 0) {
        float L = ls[0] + ls[1] + ls[2] + ls[3];
        float C = cs[0] + cs[1] + cs[2] + cs[3];
        atomicAdd(&sumcnt[0], L);
        atomicAdd(&sumcnt[1], C);
    }
}

__global__ void finalize2(const float* __restrict__ sumcnt, float* __restrict__ out) {
    float S = sumcnt[0], C = sumcnt[1];
    out[0] = (C > 0.f) ? S / fmaxf(C, 1.f) : 0.f;
}

// ---------------------------------------------------------------------------
extern "C" void kernel_launch(void* const* d_in, const int* in_sizes, int n_in,
                              void* d_out, int out_size, void* d_ws, size_t ws_size,
                              hipStream_t stream) {
    const float* E      = (const float*)d_in[0];
    const int*   labels = (const int*)d_in[1];
    float* out = (float*)d_out;
    float* ws  = (float*)d_ws;

    float*    sq      = ws;                                  // B
    float*    hp_part = ws + B;                              // NSEG*B
    float*    hn_part = ws + B + NSEG * B;                   // NSEG*B
    float*    sumcnt  = ws + B + 2 * NSEG * B;               // 2
    ushort_t* Ehi     = (ushort_t*)(ws + B + 2 * NSEG * B + 16);
    ushort_t* Elo     = Ehi + (size_t)B * D;

    prep_kernel<<<B / 4, 256, 0, stream>>>(E, sq, Ehi, Elo, sumcnt);
    mine_mfma<<<32 * 32, 256, 0, stream>>>(Ehi, Elo, labels, sq, hp_part, hn_part);
    finalize1<<<B / 256, 256, 0, stream>>>(hp_part, hn_part, sumcnt);
    finalize2<<<1, 1, 0, stream>>>(sumcnt, out);
}

// Round 6
// 103.677 us; speedup vs baseline: 4.3693x; 1.3977x over previous
//
#include <hip/hip_runtime.h>
#include <math.h>

typedef unsigned short ushort_t;
typedef unsigned int uint_t;
typedef __attribute__((ext_vector_type(8))) short short8;   // 8 bf16 (4 VGPRs)
typedef __attribute__((ext_vector_type(4))) float f32x4;    // MFMA acc

#define B 4096
#define D 512
#define MARGIN 0.3f
#define EPSD 1e-12f
#define NSEG 64            // 32 col-tiles x 2 col-half-waves

__device__ inline ushort_t f2bf_rn(float x) {
    uint_t u = __float_as_uint(x);
    uint_t r = (u + 0x7fffu + ((u >> 16) & 1u)) >> 16;
    return (ushort_t)r;
}
__device__ inline void gload_lds16(const void* g, void* l) {
    __builtin_amdgcn_global_load_lds(
        (const __attribute__((address_space(1))) void*)g,
        (__attribute__((address_space(3))) void*)l, 16, 0, 0);
}

// ---------------------------------------------------------------------------
// Kernel 1: per-row sqnorm (fp32, exact) + fp32 -> bf16 conversion. One wave/row.
// Also zeroes the sum/count/ticket accumulators (gid 0) — re-done every call.
// ---------------------------------------------------------------------------
__global__ __launch_bounds__(256) void prep_kernel(const float* __restrict__ E,
                                                   float* __restrict__ sq,
                                                   ushort_t* __restrict__ Ehi,
                                                   float* __restrict__ sumcnt,
                                                   int* __restrict__ ticket) {
    int gid  = blockIdx.x * 256 + threadIdx.x;
    int w    = gid >> 6;          // row
    int lane = gid & 63;
    const float4* row = (const float4*)(E + (size_t)w * D);
    float4 a = row[lane];
    float4 b = row[lane + 64];

    float s = a.x * a.x + a.y * a.y + a.z * a.z + a.w * a.w
            + b.x * b.x + b.y * b.y + b.z * b.z + b.w * b.w;
#pragma unroll
    for (int o = 32; o; o >>= 1) s += __shfl_down(s, o);
    if (lane == 0) sq[w] = s;

    float va[8] = {a.x, a.y, a.z, a.w, b.x, b.y, b.z, b.w};
    ushort_t hi[8];
#pragma unroll
    for (int i = 0; i < 8; ++i) hi[i] = f2bf_rn(va[i]);
    ushort4* ph = (ushort4*)(Ehi + (size_t)w * D);
    ph[lane]      = make_ushort4(hi[0], hi[1], hi[2], hi[3]);
    ph[lane + 64] = make_ushort4(hi[4], hi[5], hi[6], hi[7]);

    if (gid == 0) { sumcnt[0] = 0.f; sumcnt[1] = 0.f; ticket[0] = 0; }
}

// ---------------------------------------------------------------------------
// Kernel 2: MFMA distance + batch-hard mining. 128x128 tile/block, 4 waves 2x2.
// Pure-bf16 dot (error ~2e-3 per dist; loss threshold 0.109 — 10x margin).
// LDS [128 rows][32 k] bf16, 64 B/row; phys 16B-slot = logical ^ ((row>>1)&3)
// (pre-swizzled global source, linear global_load_lds dest; reads 2-way = free).
// ---------------------------------------------------------------------------
__global__ __launch_bounds__(256) void mine_mfma(const ushort_t* __restrict__ Ehi,
                                                 const int* __restrict__ labels,
                                                 const float* __restrict__ sq,
                                                 float* __restrict__ hp_part,
                                                 float* __restrict__ hn_part) {
    __shared__ short8 a8[512];               // 8 KB: A tile
    __shared__ short8 b8[512];               // 8 KB: B tile
    __shared__ float  sqr_s[128], sqc_s[128];
    __shared__ int    labr_s[128], labc_s[128];
    char* aB = (char*)a8;
    char* bB = (char*)b8;

    const int tid = threadIdx.x;
    const int w   = tid >> 6;                // wave 0..3
    const int l   = tid & 63;
    const int rt  = blockIdx.x & 31;
    const int ct  = blockIdx.x >> 5;
    const int r0  = rt * 128;
    const int c0  = ct * 128;
    const int wm  = w >> 1;                  // 0..1 row-half
    const int wn  = w & 1;                   // 0..1 col-half

    if (tid < 128) {
        sqr_s[tid]  = sq[r0 + tid];
        labr_s[tid] = labels[r0 + tid];
    } else {
        int t = tid - 128;
        sqc_s[t]  = sq[c0 + t];
        labc_s[t] = labels[c0 + t];
    }

    f32x4 acc[4][4] = {};

    const int srow  = (l >> 2);              // 0..15 within a 16-row group
    const int pslot = (l & 3);               // phys 16B slot

    for (int t = 0; t < 16; ++t) {
        const int kk = t * 32;
        if (t) __syncthreads();              // prev compute done reading LDS
#pragma unroll
        for (int i = 0; i < 2; ++i) {
            int rowL  = w * 32 + i * 16 + srow;
            int chunk = pslot ^ ((rowL >> 1) & 3);     // logical 16B chunk
            gload_lds16(Ehi + (size_t)(r0 + rowL) * D + kk + chunk * 8,
                        aB + (w * 32 + i * 16) * 64);
            gload_lds16(Ehi + (size_t)(c0 + rowL) * D + kk + chunk * 8,
                        bB + (w * 32 + i * 16) * 64);
        }
        __syncthreads();                      // compiler drains vmcnt before barrier

        short8 af[4], bf[4];
#pragma unroll
        for (int f = 0; f < 4; ++f) {
            int rrA = wm * 64 + f * 16 + (l & 15);
            int sA  = (l >> 4) ^ ((rrA >> 1) & 3);
            af[f] = *(const short8*)(aB + rrA * 64 + sA * 16);
            int rrB = wn * 64 + f * 16 + (l & 15);
            int sB  = (l >> 4) ^ ((rrB >> 1) & 3);
            bf[f] = *(const short8*)(bB + rrB * 64 + sB * 16);
        }
#pragma unroll
        for (int fm = 0; fm < 4; ++fm)
#pragma unroll
            for (int fn = 0; fn < 4; ++fn)
                acc[fm][fn] = __builtin_amdgcn_mfma_f32_16x16x32_bf16(
                    af[fm], bf[fn], acc[fm][fn], 0, 0, 0);
    }

    // epilogue: C/D layout col = lane&15, row = (lane>>4)*4 + reg  [m89]
#pragma unroll
    for (int fm = 0; fm < 4; ++fm) {
        const int rbase = wm * 64 + fm * 16 + ((l >> 4) << 2);
        float hp[4], hn[4], sqr[4];
        int   labr[4];
#pragma unroll
        for (int r = 0; r < 4; ++r) {
            sqr[r]  = sqr_s[rbase + r];
            labr[r] = labr_s[rbase + r];
            hp[r] = -INFINITY;
            hn[r] =  INFINITY;
        }
#pragma unroll
        for (int fn = 0; fn < 4; ++fn) {
            const int cl   = wn * 64 + fn * 16 + (l & 15);
            const float sqc = sqc_s[cl];
            const int  labc = labc_s[cl];
            const int  gcol = c0 + cl;
#pragma unroll
            for (int r = 0; r < 4; ++r) {
                float d2   = sqr[r] + sqc - 2.f * acc[fm][fn][r];
                float dist = sqrtf(fmaxf(d2, EPSD));
                bool same  = (labr[r] == labc);
                bool diag  = ((r0 + rbase + r) == gcol);
                if (same && !diag) hp[r] = fmaxf(hp[r], dist);
                if (!same)         hn[r] = fminf(hn[r], dist);
            }
        }
#pragma unroll
        for (int r = 0; r < 4; ++r) {
#pragma unroll
            for (int m = 1; m < 16; m <<= 1) {
                hp[r] = fmaxf(hp[r], __shfl_xor(hp[r], m));
                hn[r] = fminf(hn[r], __shfl_xor(hn[r], m));
            }
        }
        if ((l & 15) == 0) {
            const int p = ct * 2 + wn;
#pragma unroll
            for (int r = 0; r < 4; ++r) {
                hp_part[(size_t)p * B + r0 + rbase + r] = hp[r];
                hn_part[(size_t)p * B + r0 + rbase + r] = hn[r];
            }
        }
    }
}

// ---------------------------------------------------------------------------
// Kernel 3: combine segments, masked mean, last block writes out.
// ---------------------------------------------------------------------------
__global__ __launch_bounds__(256) void finalize_kernel(const float* __restrict__ hp_part,
                                                       const float* __restrict__ hn_part,
                                                       float* __restrict__ sumcnt,
                                                       int* __restrict__ ticket,
                                                       float* __restrict__ out) {
    const int r = blockIdx.x * 256 + threadIdx.x;
    float hp = -INFINITY, hn = INFINITY;
#pragma unroll 8
    for (int s = 0; s < NSEG; ++s) {
        hp = fmaxf(hp, hp_part[(size_t)s * B + r]);
        hn = fminf(hn, hn_part[(size_t)s * B + r]);
    }
    bool valid = (hp > -INFINITY) && (hn < INFINITY);
    float loss = valid ? fmaxf(hp - hn + MARGIN, 0.f) : 0.f;
    float cnt  = valid ? 1.f : 0.f;
#pragma unroll
    for (int o = 32; o; o >>= 1) {
        loss += __shfl_down(loss, o);
        cnt  += __shfl_down(cnt, o);
    }
    __shared__ float ls[4], cs[4];
    int lane = threadIdx.x & 63, wv = threadIdx.x >> 6;
    if (lane == 0) { ls[wv] = loss; cs[wv] = cnt; }
    __syncthreads();
    if (threadIdx.x == 0) {
        atomicAdd(&sumcnt[0], ls[0] + ls[1] + ls[2] + ls[3]);
        atomicAdd(&sumcnt[1], cs[0] + cs[1] + cs[2] + cs[3]);
        __threadfence();
        int t = atomicAdd(ticket, 1);
        if (t == (int)gridDim.x - 1) {
            float S = atomicAdd(&sumcnt[0], 0.f);   // coherent read-back
            float C = atomicAdd(&sumcnt[1], 0.f);
            out[0] = (C > 0.f) ? S / fmaxf(C, 1.f) : 0.f;
        }
    }
}

// ---------------------------------------------------------------------------
extern "C" void kernel_launch(void* const* d_in, const int* in_sizes, int n_in,
                              void* d_out, int out_size, void* d_ws, size_t ws_size,
                              hipStream_t stream) {
    const float* E      = (const float*)d_in[0];
    const int*   labels = (const int*)d_in[1];
    float* out = (float*)d_out;
    float* ws  = (float*)d_ws;

    float*    sq      = ws;                                  // B
    float*    hp_part = ws + B;                              // NSEG*B
    float*    hn_part = ws + B + NSEG * B;                   // NSEG*B
    float*    sumcnt  = ws + B + 2 * NSEG * B;               // 2
    int*      ticket  = (int*)(ws + B + 2 * NSEG * B + 8);   // 1
    ushort_t* Ehi     = (ushort_t*)(ws + B + 2 * NSEG * B + 16);

    prep_kernel<<<B / 4, 256, 0, stream>>>(E, sq, Ehi, sumcnt, ticket);
    mine_mfma<<<32 * 32, 256, 0, stream>>>(Ehi, labels, sq, hp_part, hn_part);
    finalize_kernel<<<B / 256, 256, 0, stream>>>(hp_part, hn_part, sumcnt, ticket, out);
}